// Round 1
// baseline (1445.039 us; speedup 1.0000x reference)
//
#include <hip/hip_runtime.h>
#include <cstdint>

#define M_ROWS 16384

__device__ __forceinline__ unsigned long long umin64(unsigned long long a,
                                                     unsigned long long b) {
  return a < b ? a : b;
}

// ---------------------------------------------------------------------------
// GEMM: Y[M x N] = relu(X[M x K] @ W[K x N] + bias), row-major, M = 16384.
// 64x64 block tile, 256 threads, 4x4 register tile per thread, BK=16.
// ---------------------------------------------------------------------------
__global__ __launch_bounds__(256) void gemm_bias_relu(
    const float* __restrict__ X, int ldx,
    const float* __restrict__ W,
    const float* __restrict__ bias,
    float* __restrict__ Y, int ldy,
    int N, int K)
{
  __shared__ __align__(16) float As[16][68];  // As[k][m]
  __shared__ __align__(16) float Bs[16][68];  // Bs[k][n]
  int tid = threadIdx.x;
  int tx = tid & 15, ty = tid >> 4;
  int m0 = blockIdx.y << 6, n0 = blockIdx.x << 6;
  float acc[4][4] = {};
  for (int k0 = 0; k0 < K; k0 += 16) {
#pragma unroll
    for (int i = 0; i < 4; i++) {
      int idx = tid + (i << 8);
      int m = idx >> 4, k = idx & 15;
      As[k][m] = (k0 + k < K) ? X[(size_t)(m0 + m) * ldx + k0 + k] : 0.f;
    }
#pragma unroll
    for (int i = 0; i < 4; i++) {
      int idx = tid + (i << 8);
      int n = idx & 63, k = idx >> 6;
      Bs[k][n] = (k0 + k < K) ? W[(size_t)(k0 + k) * N + n0 + n] : 0.f;
    }
    __syncthreads();
#pragma unroll
    for (int k = 0; k < 16; k++) {
      float4 a4 = *(const float4*)&As[k][ty << 2];
      float4 b4 = *(const float4*)&Bs[k][tx << 2];
      float av[4] = {a4.x, a4.y, a4.z, a4.w};
      float bv[4] = {b4.x, b4.y, b4.z, b4.w};
#pragma unroll
      for (int i = 0; i < 4; i++)
#pragma unroll
        for (int j = 0; j < 4; j++)
          acc[i][j] += av[i] * bv[j];
    }
    __syncthreads();
  }
  float4 bb = *(const float4*)&bias[n0 + (tx << 2)];
  float bv[4] = {bb.x, bb.y, bb.z, bb.w};
#pragma unroll
  for (int i = 0; i < 4; i++) {
    int m = m0 + (ty << 2) + i;
    float4 o;
    o.x = fmaxf(acc[i][0] + bv[0], 0.f);
    o.y = fmaxf(acc[i][1] + bv[1], 0.f);
    o.z = fmaxf(acc[i][2] + bv[2], 0.f);
    o.w = fmaxf(acc[i][3] + bv[3], 0.f);
    *(float4*)&Y[(size_t)m * ldy + n0 + (tx << 2)] = o;
  }
}

// ---------------------------------------------------------------------------
// SA1 KNN (k=32) on 2-D points + mean of per-point features G1 (64ch).
// One block (256 threads) per query. Key = (bits(d2) << 32) | local_index
// -> min-selection == stable argsort by distance with index tie-break.
// ---------------------------------------------------------------------------
__global__ __launch_bounds__(256) void knn_mean_kernel(
    const float* __restrict__ X,    // (16384, 2)
    const float* __restrict__ G1,   // (16384, 64)
    float* __restrict__ X1)         // (16384, 64)
{
  int q = blockIdx.x;
  int base = q & ~2047;
  int tid = threadIdx.x;
  __shared__ unsigned long long red[256];
  __shared__ unsigned long long winner;
  __shared__ int sel[32];
  float qx = X[(size_t)q * 2], qy = X[(size_t)q * 2 + 1];
  unsigned long long key[8];
#pragma unroll
  for (int u = 0; u < 8; u++) {
    int j = tid + (u << 8);
    float dx = X[(size_t)(base + j) * 2] - qx;
    float dy = X[(size_t)(base + j) * 2 + 1] - qy;
    float d2 = dx * dx + dy * dy;
    key[u] = ((unsigned long long)__float_as_uint(d2) << 32) | (unsigned)j;
  }
  for (int r = 0; r < 32; r++) {
    unsigned long long m = key[0];
#pragma unroll
    for (int u = 1; u < 8; u++) m = umin64(m, key[u]);
    red[tid] = m;
    __syncthreads();
    if (tid < 64) {
      unsigned long long v = umin64(umin64(red[tid], red[tid + 64]),
                                    umin64(red[tid + 128], red[tid + 192]));
      for (int off = 32; off > 0; off >>= 1) {
        unsigned long long o = __shfl_down(v, off);
        v = umin64(v, o);
      }
      if (tid == 0) {
        winner = v;
        sel[r] = (int)(v & 0xffffffffULL);
      }
    }
    __syncthreads();
    unsigned long long w = winner;
#pragma unroll
    for (int u = 0; u < 8; u++)
      if (key[u] == w) key[u] = ~0ULL;
  }
  __syncthreads();
  if (tid < 64) {
    float acc = 0.f;
#pragma unroll 4
    for (int s = 0; s < 32; s++)
      acc += G1[(size_t)(base + sel[s]) * 64 + tid];
    X1[(size_t)q * 64 + tid] = acc * (1.0f / 32.0f);
  }
}

// ---------------------------------------------------------------------------
// Ball-query pass 1: 2048-bit membership mask per query (d2 <= r2).
// GEMM-shaped: block = 64 queries x (4 tiles of 64 cands), 4x4 reg tile.
// Channel sum sequential (matches reference numerics at the boundary).
// ---------------------------------------------------------------------------
template <int C>
__global__ __launch_bounds__(256) void ball_mask_kernel(
    const float* __restrict__ F,               // (16384, C)
    unsigned long long* __restrict__ mask,     // (16384, 32) u64 words
    float r2)
{
  __shared__ __align__(16) float As[16][68];
  __shared__ __align__(16) float Bs[16][68];
  int tid = threadIdx.x;
  int tx = tid & 15, ty = tid >> 4;
  int q0 = blockIdx.y << 6;
  int base = q0 & ~2047;
  for (int ct = blockIdx.x << 2; ct < (blockIdx.x << 2) + 4; ct++) {
    int c0 = base + (ct << 6);
    float acc[4][4] = {};
    for (int k0 = 0; k0 < C; k0 += 16) {
#pragma unroll
      for (int i = 0; i < 4; i++) {
        int idx = tid + (i << 8);
        int m = idx >> 4, k = idx & 15;
        As[k][m] = F[(size_t)(q0 + m) * C + k0 + k];
      }
#pragma unroll
      for (int i = 0; i < 4; i++) {
        int idx = tid + (i << 8);
        int m = idx >> 4, k = idx & 15;
        Bs[k][m] = F[(size_t)(c0 + m) * C + k0 + k];
      }
      __syncthreads();
#pragma unroll
      for (int k = 0; k < 16; k++) {
        float4 a4 = *(const float4*)&As[k][ty << 2];
        float4 b4 = *(const float4*)&Bs[k][tx << 2];
        float av[4] = {a4.x, a4.y, a4.z, a4.w};
        float bv[4] = {b4.x, b4.y, b4.z, b4.w};
#pragma unroll
        for (int i = 0; i < 4; i++)
#pragma unroll
          for (int j = 0; j < 4; j++) {
            float d = av[i] - bv[j];
            acc[i][j] += d * d;
          }
      }
      __syncthreads();
    }
#pragma unroll
    for (int i = 0; i < 4; i++) {
      unsigned long long w = 0;
#pragma unroll
      for (int j = 0; j < 4; j++)
        if (acc[i][j] <= r2) w |= 1ULL << ((tx << 2) + j);
      for (int s = 1; s <= 8; s <<= 1)
        w |= __shfl_xor(w, s);
      if (tx == 0) mask[(size_t)(q0 + (ty << 2) + i) * 32 + ct] = w;
    }
  }
}

// ---------------------------------------------------------------------------
// Ball-query pass 2: weighted mean over members with cyclic-repeat weights.
// w_p = (floor((S-1-p)/c)+1)/S for p < min(c,S).  Block = CH threads (1/ch).
// ---------------------------------------------------------------------------
__global__ void ball_gather_kernel(
    const unsigned long long* __restrict__ mask,
    const float* __restrict__ H, int CH,
    float* __restrict__ Y, int ldy, int S)
{
  int q = blockIdx.x;
  int base = q & ~2047;
  int tid = threadIdx.x;
  __shared__ unsigned long long words[32];
  __shared__ float wtab[64];
  __shared__ int scount;
  if (tid < 32) words[tid] = mask[(size_t)q * 32 + tid];
  __syncthreads();
  if (tid == 0) {
    int c = 0;
    for (int w = 0; w < 32; w++) c += __popcll(words[w]);
    scount = c;
  }
  __syncthreads();
  int c = scount;
  if (tid < 64) {
    int p = tid;
    int cnt = (p < c && p < S) ? ((S - 1 - p) / c + 1) : 0;
    wtab[p] = (float)cnt / (float)S;
  }
  __syncthreads();
  float acc = 0.f;
  int p = 0;
  int lim = c < S ? c : S;
  for (int w = 0; w < 32 && p < lim; w++) {
    unsigned long long m = words[w];
    while (m && p < lim) {
      int j = (w << 6) + __builtin_ctzll(m);
      m &= m - 1;
      acc += wtab[p] * H[(size_t)(base + j) * CH + tid];
      p++;
    }
  }
  Y[(size_t)q * ldy + tid] = acc;
}

// ---------------------------------------------------------------------------
// Final head: out = sigmoid(F2[q] . w + b).  One block (128 thr) per point.
// ---------------------------------------------------------------------------
__global__ __launch_bounds__(128) void out_kernel(
    const float* __restrict__ F2,   // (16384, 128)
    const float* __restrict__ w,
    const float* __restrict__ bias,
    float* __restrict__ out)
{
  int q = blockIdx.x, tid = threadIdx.x;
  float v = F2[(size_t)q * 128 + tid] * w[tid];
  for (int off = 32; off > 0; off >>= 1) v += __shfl_down(v, off);
  __shared__ float part[2];
  if ((tid & 63) == 0) part[tid >> 6] = v;
  __syncthreads();
  if (tid == 0) {
    float s = part[0] + part[1] + bias[0];
    out[q] = 1.f / (1.f + expf(-s));
  }
}

// ---------------------------------------------------------------------------
extern "C" void kernel_launch(void* const* d_in, const int* in_sizes, int n_in,
                              void* d_out, int out_size, void* d_ws,
                              size_t ws_size, hipStream_t stream)
{
  const float* x      = (const float*)d_in[0];
  const float* sa1_w0 = (const float*)d_in[1];
  const float* sa1_b0 = (const float*)d_in[2];
  const float* sa1_w1 = (const float*)d_in[3];
  const float* sa1_b1 = (const float*)d_in[4];
  const float* sa2_w0 = (const float*)d_in[5];
  const float* sa2_b0 = (const float*)d_in[6];
  const float* sa2_w1 = (const float*)d_in[7];
  const float* sa2_b1 = (const float*)d_in[8];
  const float* sa3_w0 = (const float*)d_in[9];
  const float* sa3_b0 = (const float*)d_in[10];
  const float* sa3_w1 = (const float*)d_in[11];
  const float* sa3_b1 = (const float*)d_in[12];
  const float* fp1_w0 = (const float*)d_in[13];
  const float* fp1_b0 = (const float*)d_in[14];
  const float* fp1_w1 = (const float*)d_in[15];
  const float* fp1_b1 = (const float*)d_in[16];
  const float* fp2_w0 = (const float*)d_in[17];
  const float* fp2_b0 = (const float*)d_in[18];
  const float* fp2_w1 = (const float*)d_in[19];
  const float* fp2_b1 = (const float*)d_in[20];
  const float* fc1_w  = (const float*)d_in[21];
  const float* fc1_b  = (const float*)d_in[22];
  const float* fc2_w  = (const float*)d_in[23];
  const float* fc2_b  = (const float*)d_in[24];
  const float* out_w  = (const float*)d_in[25];
  const float* out_b  = (const float*)d_in[26];
  float* out = (float*)d_out;

  const size_t M = M_ROWS;
  float* ws = (float*)d_ws;
  // Workspace layout (floats). Total = M * 2432 = ~160 MB.
  float* T  = ws;                    // M*256 temp (MLP intermediates; G1 lives at T+M*64 early on)
  float* G1 = T + M * 64;            // M*64  (SA1 per-point features; dead after knn)
  float* X1 = T + M * 256;           // M*64
  float* X2 = X1 + M * 64;           // M*128
  float* H2 = X2 + M * 128;          // M*128 (later reused as fc2 out)
  float* H3 = H2 + M * 128;          // M*256 (later reused as fc1 out)
  unsigned long long* MASK = (unsigned long long*)(H3 + M * 256);  // M*32 u64
  float* FA = (float*)MASK + M * 64; // M*512 (fp1 hidden)
  float* G  = FA + M * 512;          // M*1024 concat [fp2|fp1|x3]
  if (ws_size < (size_t)M * 2432 * sizeof(float)) return;  // refuse OOB

  dim3 blk(256);
  // SA1: per-point MLP 2->64->64, then knn(k=32) mean.
  gemm_bias_relu<<<dim3(1, 256), blk, 0, stream>>>(x, 2, sa1_w0, sa1_b0, T, 64, 64, 2);
  gemm_bias_relu<<<dim3(1, 256), blk, 0, stream>>>(T, 64, sa1_w1, sa1_b1, G1, 64, 64, 64);
  knn_mean_kernel<<<16384, 256, 0, stream>>>(x, G1, X1);
  // SA2: per-point MLP 64->128->128, ball(r=0.2, S=32) weighted mean.
  gemm_bias_relu<<<dim3(2, 256), blk, 0, stream>>>(X1, 64, sa2_w0, sa2_b0, T, 128, 128, 64);
  gemm_bias_relu<<<dim3(2, 256), blk, 0, stream>>>(T, 128, sa2_w1, sa2_b1, H2, 128, 128, 128);
  ball_mask_kernel<64><<<dim3(8, 256), blk, 0, stream>>>(X1, MASK, 0.2f * 0.2f);
  ball_gather_kernel<<<16384, 128, 0, stream>>>(MASK, H2, 128, X2, 128, 32);
  // SA3: per-point MLP 128->256->256, ball(r=0.4, S=64) weighted mean -> G cols 768:1024.
  gemm_bias_relu<<<dim3(4, 256), blk, 0, stream>>>(X2, 128, sa3_w0, sa3_b0, T, 256, 256, 128);
  gemm_bias_relu<<<dim3(4, 256), blk, 0, stream>>>(T, 256, sa3_w1, sa3_b1, H3, 256, 256, 256);
  ball_mask_kernel<128><<<dim3(8, 256), blk, 0, stream>>>(X2, MASK, 0.4f * 0.4f);
  ball_gather_kernel<<<16384, 256, 0, stream>>>(MASK, H3, 256, G + 768, 1024, 64);
  // FP1: x2 -> 512 -> 512 -> G cols 256:768.
  gemm_bias_relu<<<dim3(8, 256), blk, 0, stream>>>(X2, 128, fp1_w0, fp1_b0, FA, 512, 512, 128);
  gemm_bias_relu<<<dim3(8, 256), blk, 0, stream>>>(FA, 512, fp1_w1, fp1_b1, G + 256, 1024, 512, 512);
  // FP2: x1 -> 256 -> 256 -> G cols 0:256.
  gemm_bias_relu<<<dim3(4, 256), blk, 0, stream>>>(X1, 64, fp2_w0, fp2_b0, T, 256, 256, 64);
  gemm_bias_relu<<<dim3(4, 256), blk, 0, stream>>>(T, 256, fp2_w1, fp2_b1, G, 1024, 256, 256);
  // Head: 1024 -> 256 -> 128 -> sigmoid(128 -> 1).
  gemm_bias_relu<<<dim3(4, 256), blk, 0, stream>>>(G, 1024, fc1_w, fc1_b, H3, 256, 256, 1024);
  gemm_bias_relu<<<dim3(2, 256), blk, 0, stream>>>(H3, 256, fc2_w, fc2_b, H2, 128, 128, 256);
  out_kernel<<<16384, 128, 0, stream>>>(H2, out_w, out_b, out);
}

// Round 2
// 1072.802 us; speedup vs baseline: 1.3470x; 1.3470x over previous
//
#include <hip/hip_runtime.h>
#include <hip/hip_bf16.h>
#include <cstdint>

#define M_ROWS 16384

typedef __attribute__((ext_vector_type(8))) short short8;
typedef __attribute__((ext_vector_type(4))) float f32x4;

__device__ __forceinline__ unsigned long long umin64(unsigned long long a,
                                                     unsigned long long b) {
  return a < b ? a : b;
}

// ---------------------------------------------------------------------------
// fp32 GEMM (kept for SA1/SA2 whose outputs feed ball masks — must stay
// bit-identical): Y = relu(X@W + b), 64x64 tile, 4x4/thread, BK=16.
// ---------------------------------------------------------------------------
__global__ __launch_bounds__(256) void gemm_bias_relu(
    const float* __restrict__ X, int ldx,
    const float* __restrict__ W,
    const float* __restrict__ bias,
    float* __restrict__ Y, int ldy,
    int N, int K)
{
  __shared__ __align__(16) float As[16][68];
  __shared__ __align__(16) float Bs[16][68];
  int tid = threadIdx.x;
  int tx = tid & 15, ty = tid >> 4;
  int m0 = blockIdx.y << 6, n0 = blockIdx.x << 6;
  float acc[4][4] = {};
  for (int k0 = 0; k0 < K; k0 += 16) {
#pragma unroll
    for (int i = 0; i < 4; i++) {
      int idx = tid + (i << 8);
      int m = idx >> 4, k = idx & 15;
      As[k][m] = (k0 + k < K) ? X[(size_t)(m0 + m) * ldx + k0 + k] : 0.f;
    }
#pragma unroll
    for (int i = 0; i < 4; i++) {
      int idx = tid + (i << 8);
      int n = idx & 63, k = idx >> 6;
      Bs[k][n] = (k0 + k < K) ? W[(size_t)(k0 + k) * N + n0 + n] : 0.f;
    }
    __syncthreads();
#pragma unroll
    for (int k = 0; k < 16; k++) {
      float4 a4 = *(const float4*)&As[k][ty << 2];
      float4 b4 = *(const float4*)&Bs[k][tx << 2];
      float av[4] = {a4.x, a4.y, a4.z, a4.w};
      float bv[4] = {b4.x, b4.y, b4.z, b4.w};
#pragma unroll
      for (int i = 0; i < 4; i++)
#pragma unroll
        for (int j = 0; j < 4; j++)
          acc[i][j] += av[i] * bv[j];
    }
    __syncthreads();
  }
  float4 bb = *(const float4*)&bias[n0 + (tx << 2)];
  float bv[4] = {bb.x, bb.y, bb.z, bb.w};
#pragma unroll
  for (int i = 0; i < 4; i++) {
    int m = m0 + (ty << 2) + i;
    float4 o;
    o.x = fmaxf(acc[i][0] + bv[0], 0.f);
    o.y = fmaxf(acc[i][1] + bv[1], 0.f);
    o.z = fmaxf(acc[i][2] + bv[2], 0.f);
    o.w = fmaxf(acc[i][3] + bv[3], 0.f);
    *(float4*)&Y[(size_t)m * ldy + n0 + (tx << 2)] = o;
  }
}

// ---------------------------------------------------------------------------
// Weight prep: W (K x N) fp32 -> Wt (N x K) bf16.
// ---------------------------------------------------------------------------
__global__ __launch_bounds__(256) void transpose_cast(
    const float* __restrict__ W, __hip_bfloat16* __restrict__ Wt, int K, int N)
{
  __shared__ float tile[32][33];
  int n0 = blockIdx.x << 5, k0 = blockIdx.y << 5;
  int j = threadIdx.x & 31, i0 = threadIdx.x >> 5;
#pragma unroll
  for (int p = 0; p < 4; p++) {
    int i = i0 + p * 8;
    tile[i][j] = W[(size_t)(k0 + i) * N + n0 + j];
  }
  __syncthreads();
#pragma unroll
  for (int p = 0; p < 4; p++) {
    int r = i0 + p * 8;
    Wt[(size_t)(n0 + r) * K + k0 + j] = (__hip_bfloat16)tile[j][r];
  }
}

// ---------------------------------------------------------------------------
// bf16 MFMA GEMM: Y = relu(A(bf16, MxK) @ Wt^T(bf16, NxK) + bias(f32)).
// 128x128 block tile, 4 waves (2x2), each wave 64x64 via 4x4 of 16x16x32
// MFMA. LDS rows padded to 40 bf16 (80B: 16B-aligned, 2-way banks = free).
// A-frag: A[m=lane&15][k=quad*8+j]; B-frag: B[k=quad*8+j][n=lane&15];
// D: col=lane&15, row=quad*4+reg (verified layouts, guide §3).
// ---------------------------------------------------------------------------
template <bool OUT_BF16>
__global__ __launch_bounds__(256) void gemm_mfma(
    const __hip_bfloat16* __restrict__ A, int lda,
    const __hip_bfloat16* __restrict__ Wt, int ldw,
    const float* __restrict__ bias,
    void* __restrict__ Y, int ldy, int N, int K)
{
  __shared__ __align__(16) short As[128][40];
  __shared__ __align__(16) short Bs[128][40];
  int tid = threadIdx.x;
  int wave = tid >> 6, lane = tid & 63;
  int quad = lane >> 4, l16 = lane & 15;
  int m0 = blockIdx.y << 7, n0 = blockIdx.x << 7;
  int wm = (wave >> 1) << 6, wn = (wave & 1) << 6;
  f32x4 acc[4][4] = {};
  const short* Ag = (const short*)A;
  const short* Bg = (const short*)Wt;
  int srow = tid >> 2, sq = tid & 3;
  for (int k0 = 0; k0 < K; k0 += 32) {
#pragma unroll
    for (int h = 0; h < 2; h++) {
      int r = srow + (h << 6);
      uint4 va = *(const uint4*)&Ag[(size_t)(m0 + r) * lda + k0 + sq * 8];
      *(uint4*)&As[r][sq * 8] = va;
      uint4 vb = *(const uint4*)&Bg[(size_t)(n0 + r) * ldw + k0 + sq * 8];
      *(uint4*)&Bs[r][sq * 8] = vb;
    }
    __syncthreads();
    short8 a[4], b[4];
#pragma unroll
    for (int mi = 0; mi < 4; mi++)
      a[mi] = *(const short8*)&As[wm + mi * 16 + l16][quad * 8];
#pragma unroll
    for (int ni = 0; ni < 4; ni++)
      b[ni] = *(const short8*)&Bs[wn + ni * 16 + l16][quad * 8];
#pragma unroll
    for (int mi = 0; mi < 4; mi++)
#pragma unroll
      for (int ni = 0; ni < 4; ni++)
        acc[mi][ni] = __builtin_amdgcn_mfma_f32_16x16x32_bf16(
            a[mi], b[ni], acc[mi][ni], 0, 0, 0);
    __syncthreads();
  }
  float bn[4];
#pragma unroll
  for (int ni = 0; ni < 4; ni++) bn[ni] = bias[n0 + wn + ni * 16 + l16];
#pragma unroll
  for (int mi = 0; mi < 4; mi++)
#pragma unroll
    for (int ni = 0; ni < 4; ni++) {
      int n = n0 + wn + ni * 16 + l16;
#pragma unroll
      for (int r = 0; r < 4; r++) {
        int m = m0 + wm + mi * 16 + quad * 4 + r;
        float v = fmaxf(acc[mi][ni][r] + bn[ni], 0.f);
        if (OUT_BF16)
          ((__hip_bfloat16*)Y)[(size_t)m * ldy + n] = (__hip_bfloat16)v;
        else
          ((float*)Y)[(size_t)m * ldy + n] = v;
      }
    }
}

// ---------------------------------------------------------------------------
// SA1 KNN (k=32) + mean of G1; also emits bf16 copy of X1.
// ---------------------------------------------------------------------------
__global__ __launch_bounds__(256) void knn_mean_kernel(
    const float* __restrict__ X,
    const float* __restrict__ G1,
    float* __restrict__ X1,
    __hip_bfloat16* __restrict__ X1b)
{
  int q = blockIdx.x;
  int base = q & ~2047;
  int tid = threadIdx.x;
  __shared__ unsigned long long red[256];
  __shared__ unsigned long long winner;
  __shared__ int sel[32];
  float qx = X[(size_t)q * 2], qy = X[(size_t)q * 2 + 1];
  unsigned long long key[8];
#pragma unroll
  for (int u = 0; u < 8; u++) {
    int j = tid + (u << 8);
    float dx = X[(size_t)(base + j) * 2] - qx;
    float dy = X[(size_t)(base + j) * 2 + 1] - qy;
    float d2 = dx * dx + dy * dy;
    key[u] = ((unsigned long long)__float_as_uint(d2) << 32) | (unsigned)j;
  }
  for (int r = 0; r < 32; r++) {
    unsigned long long m = key[0];
#pragma unroll
    for (int u = 1; u < 8; u++) m = umin64(m, key[u]);
    red[tid] = m;
    __syncthreads();
    if (tid < 64) {
      unsigned long long v = umin64(umin64(red[tid], red[tid + 64]),
                                    umin64(red[tid + 128], red[tid + 192]));
      for (int off = 32; off > 0; off >>= 1) {
        unsigned long long o = __shfl_down(v, off);
        v = umin64(v, o);
      }
      if (tid == 0) {
        winner = v;
        sel[r] = (int)(v & 0xffffffffULL);
      }
    }
    __syncthreads();
    unsigned long long w = winner;
#pragma unroll
    for (int u = 0; u < 8; u++)
      if (key[u] == w) key[u] = ~0ULL;
  }
  __syncthreads();
  if (tid < 64) {
    float acc = 0.f;
#pragma unroll 4
    for (int s = 0; s < 32; s++)
      acc += G1[(size_t)(base + sel[s]) * 64 + tid];
    float v = acc * (1.0f / 32.0f);
    X1[(size_t)q * 64 + tid] = v;
    X1b[(size_t)q * 64 + tid] = (__hip_bfloat16)v;
  }
}

// ---------------------------------------------------------------------------
// Ball-query pass 1 v2: 128 queries x 128 cands per block, 8x8/thread.
// Per-pair channel sum remains sequential ascending-k -> bit-identical masks.
// Thread's cands: {tx*4..+3} and {64+tx*4..+3} (2-way bank groups = free).
// ---------------------------------------------------------------------------
template <int C>
__global__ __launch_bounds__(256) void ball_mask2(
    const float* __restrict__ F,
    unsigned long long* __restrict__ mask,
    float r2)
{
  __shared__ __align__(16) float As[16][132];
  __shared__ __align__(16) float Bs[16][132];
  int tid = threadIdx.x;
  int tx = tid & 15, ty = tid >> 4;
  int q0 = blockIdx.y << 7;
  int base = q0 & ~2047;
  int c0 = base + (blockIdx.x << 7);
  float acc[8][8] = {};
  for (int k0 = 0; k0 < C; k0 += 16) {
#pragma unroll
    for (int c = 0; c < 2; c++) {
      int idx = tid + (c << 8);
      int row = idx >> 2, qr = idx & 3;
      float4 va = *(const float4*)&F[(size_t)(q0 + row) * C + k0 + qr * 4];
      As[qr * 4 + 0][row] = va.x;
      As[qr * 4 + 1][row] = va.y;
      As[qr * 4 + 2][row] = va.z;
      As[qr * 4 + 3][row] = va.w;
      float4 vb = *(const float4*)&F[(size_t)(c0 + row) * C + k0 + qr * 4];
      Bs[qr * 4 + 0][row] = vb.x;
      Bs[qr * 4 + 1][row] = vb.y;
      Bs[qr * 4 + 2][row] = vb.z;
      Bs[qr * 4 + 3][row] = vb.w;
    }
    __syncthreads();
#pragma unroll
    for (int k = 0; k < 16; k++) {
      float av[8], bv[8];
      *(float4*)&av[0] = *(const float4*)&As[k][ty * 8];
      *(float4*)&av[4] = *(const float4*)&As[k][ty * 8 + 4];
      *(float4*)&bv[0] = *(const float4*)&Bs[k][tx * 4];
      *(float4*)&bv[4] = *(const float4*)&Bs[k][64 + tx * 4];
#pragma unroll
      for (int i = 0; i < 8; i++)
#pragma unroll
        for (int j = 0; j < 8; j++) {
          float d = av[i] - bv[j];
          acc[i][j] += d * d;
        }
    }
    __syncthreads();
  }
  int w0 = (blockIdx.x << 1);
#pragma unroll
  for (int i = 0; i < 8; i++) {
    unsigned long long wlo = 0, whi = 0;
#pragma unroll
    for (int j = 0; j < 4; j++) {
      if (acc[i][j] <= r2) wlo |= 1ULL << (tx * 4 + j);
      if (acc[i][4 + j] <= r2) whi |= 1ULL << (tx * 4 + j);
    }
#pragma unroll
    for (int s = 1; s <= 8; s <<= 1) {
      wlo |= __shfl_xor(wlo, s);
      whi |= __shfl_xor(whi, s);
    }
    if (tx == 0) {
      int q = q0 + ty * 8 + i;
      mask[(size_t)q * 32 + w0] = wlo;
      mask[(size_t)q * 32 + w0 + 1] = whi;
    }
  }
}

// ---------------------------------------------------------------------------
// Ball-query pass 2: weighted mean, optional fp32 and/or bf16 outputs.
// ---------------------------------------------------------------------------
__global__ void ball_gather_kernel(
    const unsigned long long* __restrict__ mask,
    const float* __restrict__ H, int CH,
    float* __restrict__ Yf, __hip_bfloat16* __restrict__ Yb,
    int ldy, int S)
{
  int q = blockIdx.x;
  int base = q & ~2047;
  int tid = threadIdx.x;
  __shared__ unsigned long long words[32];
  __shared__ float wtab[64];
  __shared__ int scount;
  if (tid < 32) words[tid] = mask[(size_t)q * 32 + tid];
  __syncthreads();
  if (tid == 0) {
    int c = 0;
    for (int w = 0; w < 32; w++) c += __popcll(words[w]);
    scount = c;
  }
  __syncthreads();
  int c = scount;
  if (tid < 64) {
    int p = tid;
    int cnt = (p < c && p < S) ? ((S - 1 - p) / c + 1) : 0;
    wtab[p] = (float)cnt / (float)S;
  }
  __syncthreads();
  float acc = 0.f;
  int p = 0;
  int lim = c < S ? c : S;
  for (int w = 0; w < 32 && p < lim; w++) {
    unsigned long long m = words[w];
    while (m && p < lim) {
      int j = (w << 6) + __builtin_ctzll(m);
      m &= m - 1;
      acc += wtab[p] * H[(size_t)(base + j) * CH + tid];
      p++;
    }
  }
  if (Yf) Yf[(size_t)q * ldy + tid] = acc;
  if (Yb) Yb[(size_t)q * ldy + tid] = (__hip_bfloat16)acc;
}

// ---------------------------------------------------------------------------
// Final head: out = sigmoid(F2[q] . w + b).
// ---------------------------------------------------------------------------
__global__ __launch_bounds__(128) void out_kernel(
    const float* __restrict__ F2,
    const float* __restrict__ w,
    const float* __restrict__ bias,
    float* __restrict__ out)
{
  int q = blockIdx.x, tid = threadIdx.x;
  float v = F2[(size_t)q * 128 + tid] * w[tid];
  for (int off = 32; off > 0; off >>= 1) v += __shfl_down(v, off);
  __shared__ float part[2];
  if ((tid & 63) == 0) part[tid >> 6] = v;
  __syncthreads();
  if (tid == 0) {
    float s = part[0] + part[1] + bias[0];
    out[q] = 1.f / (1.f + expf(-s));
  }
}

// ---------------------------------------------------------------------------
extern "C" void kernel_launch(void* const* d_in, const int* in_sizes, int n_in,
                              void* d_out, int out_size, void* d_ws,
                              size_t ws_size, hipStream_t stream)
{
  const float* x      = (const float*)d_in[0];
  const float* sa1_w0 = (const float*)d_in[1];
  const float* sa1_b0 = (const float*)d_in[2];
  const float* sa1_w1 = (const float*)d_in[3];
  const float* sa1_b1 = (const float*)d_in[4];
  const float* sa2_w0 = (const float*)d_in[5];
  const float* sa2_b0 = (const float*)d_in[6];
  const float* sa2_w1 = (const float*)d_in[7];
  const float* sa2_b1 = (const float*)d_in[8];
  const float* sa3_w0 = (const float*)d_in[9];
  const float* sa3_b0 = (const float*)d_in[10];
  const float* sa3_w1 = (const float*)d_in[11];
  const float* sa3_b1 = (const float*)d_in[12];
  const float* fp1_w0 = (const float*)d_in[13];
  const float* fp1_b0 = (const float*)d_in[14];
  const float* fp1_w1 = (const float*)d_in[15];
  const float* fp1_b1 = (const float*)d_in[16];
  const float* fp2_w0 = (const float*)d_in[17];
  const float* fp2_b0 = (const float*)d_in[18];
  const float* fp2_w1 = (const float*)d_in[19];
  const float* fp2_b1 = (const float*)d_in[20];
  const float* fc1_w  = (const float*)d_in[21];
  const float* fc1_b  = (const float*)d_in[22];
  const float* fc2_w  = (const float*)d_in[23];
  const float* fc2_b  = (const float*)d_in[24];
  const float* out_w  = (const float*)d_in[25];
  const float* out_b  = (const float*)d_in[26];
  float* out = (float*)d_out;

  const size_t M = M_ROWS;
  float* ws = (float*)d_ws;
  // fp32 buffers
  float* T   = ws;             // M*256
  float* G1  = ws + M * 256;   // M*64
  float* X1  = ws + M * 320;   // M*64
  float* X2  = ws + M * 384;   // M*128
  float* H2  = ws + M * 512;   // M*128 (sa2 out; later fc2 out)
  float* H3  = ws + M * 640;   // M*256 (sa3 out f32 for gather3)
  unsigned long long* MASK = (unsigned long long*)(ws + M * 896);  // M*32 u64
  // bf16 buffers
  __hip_bfloat16* X1b = (__hip_bfloat16*)(ws + M * 960);   // M*64
  __hip_bfloat16* X2b = (__hip_bfloat16*)(ws + M * 992);   // M*128
  __hip_bfloat16* TB  = (__hip_bfloat16*)(ws + M * 1056);  // M*512 (sa3t/fp1t/fp2t)
  __hip_bfloat16* G   = (__hip_bfloat16*)(ws + M * 1312);  // M*1024 concat
  __hip_bfloat16* H3b = (__hip_bfloat16*)(ws + M * 1824);  // M*256 (fc1 out)
  __hip_bfloat16* WB  = (__hip_bfloat16*)(ws + M * 1952);  // 802816 bf16 weights
  if (ws_size < (size_t)M * 1984 * sizeof(float)) return;
  __hip_bfloat16* w_sa3_0 = WB;               // 256x128
  __hip_bfloat16* w_sa3_1 = w_sa3_0 + 32768;  // 256x256
  __hip_bfloat16* w_fp1_0 = w_sa3_1 + 65536;  // 512x128
  __hip_bfloat16* w_fp1_1 = w_fp1_0 + 65536;  // 512x512
  __hip_bfloat16* w_fp2_0 = w_fp1_1 + 262144; // 256x64
  __hip_bfloat16* w_fp2_1 = w_fp2_0 + 16384;  // 256x256
  __hip_bfloat16* w_fc1   = w_fp2_1 + 65536;  // 256x1024
  __hip_bfloat16* w_fc2   = w_fc1 + 262144;   // 128x256

  dim3 blk(256);
  // Weight prep (Wt[n][k] = bf16(W[k][n])).
  transpose_cast<<<dim3(8, 4),   blk, 0, stream>>>(sa3_w0, w_sa3_0, 128, 256);
  transpose_cast<<<dim3(8, 8),   blk, 0, stream>>>(sa3_w1, w_sa3_1, 256, 256);
  transpose_cast<<<dim3(16, 4),  blk, 0, stream>>>(fp1_w0, w_fp1_0, 128, 512);
  transpose_cast<<<dim3(16, 16), blk, 0, stream>>>(fp1_w1, w_fp1_1, 512, 512);
  transpose_cast<<<dim3(8, 2),   blk, 0, stream>>>(fp2_w0, w_fp2_0, 64, 256);
  transpose_cast<<<dim3(8, 8),   blk, 0, stream>>>(fp2_w1, w_fp2_1, 256, 256);
  transpose_cast<<<dim3(8, 32),  blk, 0, stream>>>(fc1_w,  w_fc1, 1024, 256);
  transpose_cast<<<dim3(4, 8),   blk, 0, stream>>>(fc2_w,  w_fc2, 256, 128);

  // SA1 (fp32 exact — feeds knn mean -> X1 -> mask2).
  gemm_bias_relu<<<dim3(1, 256), blk, 0, stream>>>(x, 2, sa1_w0, sa1_b0, T, 64, 64, 2);
  gemm_bias_relu<<<dim3(1, 256), blk, 0, stream>>>(T, 64, sa1_w1, sa1_b1, G1, 64, 64, 64);
  knn_mean_kernel<<<16384, 256, 0, stream>>>(x, G1, X1, X1b);
  // SA2 (fp32 exact — feeds X2 -> mask3).
  gemm_bias_relu<<<dim3(2, 256), blk, 0, stream>>>(X1, 64, sa2_w0, sa2_b0, T, 128, 128, 64);
  gemm_bias_relu<<<dim3(2, 256), blk, 0, stream>>>(T, 128, sa2_w1, sa2_b1, H2, 128, 128, 128);
  ball_mask2<64><<<dim3(16, 128), blk, 0, stream>>>(X1, MASK, 0.2f * 0.2f);
  ball_gather_kernel<<<16384, 128, 0, stream>>>(MASK, H2, 128, X2, X2b, 128, 32);
  // SA3 MLP (bf16 MFMA — output is downstream of all masks).
  gemm_mfma<true><<<dim3(2, 128), blk, 0, stream>>>(X2b, 128, w_sa3_0, 128, sa3_b0, TB, 256, 256, 128);
  gemm_mfma<false><<<dim3(2, 128), blk, 0, stream>>>(TB, 256, w_sa3_1, 256, sa3_b1, H3, 256, 256, 256);
  ball_mask2<128><<<dim3(16, 128), blk, 0, stream>>>(X2, MASK, 0.4f * 0.4f);
  ball_gather_kernel<<<16384, 256, 0, stream>>>(MASK, H3, 256, nullptr, G + 768, 1024, 64);
  // FP1 (bf16): x2 -> 512 -> 512 -> G[256:768].
  gemm_mfma<true><<<dim3(4, 128), blk, 0, stream>>>(X2b, 128, w_fp1_0, 128, fp1_b0, TB, 512, 512, 128);
  gemm_mfma<true><<<dim3(4, 128), blk, 0, stream>>>(TB, 512, w_fp1_1, 512, fp1_b1, G + 256, 1024, 512, 512);
  // FP2 (bf16): x1 -> 256 -> 256 -> G[0:256].
  gemm_mfma<true><<<dim3(2, 128), blk, 0, stream>>>(X1b, 64, w_fp2_0, 64, fp2_b0, TB, 256, 256, 64);
  gemm_mfma<true><<<dim3(2, 128), blk, 0, stream>>>(TB, 256, w_fp2_1, 256, fp2_b1, G, 1024, 256, 256);
  // Head (bf16): 1024 -> 256 -> 128 -> sigmoid.
  gemm_mfma<true><<<dim3(2, 128), blk, 0, stream>>>(G, 1024, w_fc1, 1024, fc1_b, H3b, 256, 256, 1024);
  gemm_mfma<false><<<dim3(1, 128), blk, 0, stream>>>(H3b, 256, w_fc2, 256, fc2_b, H2, 128, 128, 256);
  out_kernel<<<16384, 128, 0, stream>>>(H2, out_w, out_b, out);
}